// Round 1
// baseline (1169.600 us; speedup 1.0000x reference)
//
#include <hip/hip_runtime.h>
#include <math.h>

#define CDIM 192
#define NHEADS 6
#define HDIM 32
#define WIN 7
#define KWIN 49
#define BATCH 4
#define PIX 3136      // 56*56
#define NIMG 24       // BATCH*NHEADS
#define EPSV 1e-5f

// ---------------- BN stats: per-channel mean / inv_std over (B,H,W) ----------
__global__ __launch_bounds__(256) void bn_stats_k(const float* __restrict__ x,
                                                  float* __restrict__ stats) {
  int c = blockIdx.x;
  float s = 0.f, q = 0.f;
  for (int n = threadIdx.x; n < BATCH * PIX; n += 256) {
    int b = n / PIX, p = n - b * PIX;
    float v = x[((size_t)b * CDIM + c) * PIX + p];
    s += v; q += v * v;
  }
  __shared__ float rs[256], rq[256];
  rs[threadIdx.x] = s; rq[threadIdx.x] = q;
  __syncthreads();
  for (int st = 128; st > 0; st >>= 1) {
    if (threadIdx.x < st) { rs[threadIdx.x] += rs[threadIdx.x + st]; rq[threadIdx.x] += rq[threadIdx.x + st]; }
    __syncthreads();
  }
  if (threadIdx.x == 0) {
    float mean = rs[0] / (float)(BATCH * PIX);
    float var = rq[0] / (float)(BATCH * PIX) - mean * mean;
    stats[c] = mean;
    stats[CDIM + c] = rsqrtf(var + EPSV);
  }
}

// ---------------- fold BN (and q-scale) into qkv weights --------------------
__global__ __launch_bounds__(192) void fold_k(const float* __restrict__ qkv_w,
                                              const float* __restrict__ qkv_b,
                                              const float* __restrict__ gamma,
                                              const float* __restrict__ beta,
                                              const float* __restrict__ stats,
                                              float* __restrict__ w_eff,
                                              float* __restrict__ b_eff) {
  int o = blockIdx.x, c = threadIdx.x;
  float alpha = gamma[c] * stats[CDIM + c];
  float shift = beta[c] - stats[c] * alpha;
  float w = qkv_w[o * CDIM + c];
  float scale = (o < CDIM) ? 0.17677669529663687f : 1.f;  // HD^-0.5 on q rows
  w_eff[o * CDIM + c] = w * alpha * scale;
  __shared__ float r[CDIM];
  r[c] = w * shift;
  __syncthreads();
  if (c == 0) {
    float s = 0.f;
    for (int i = 0; i < CDIM; i++) s += r[i];
    b_eff[o] = (qkv_b[o] + s) * scale;
  }
}

// ---------------- tiled fp32 1x1-conv GEMM: Y[b,o,p] = sum_c W[o,c] X[b,c,p] -
#define EPI_QKV 0
#define EPI_ADD 1
#define EPI_GELU 2

template <int EPI>
__global__ __launch_bounds__(256) void gemm_k(const float* __restrict__ X,
                                              const float* __restrict__ W,
                                              const float* __restrict__ bias,
                                              float* __restrict__ Y,
                                              const float* __restrict__ extra,
                                              float* __restrict__ Y2,
                                              int Cin, int Cout) {
  __shared__ __align__(16) float Xs[64][68];
  __shared__ __align__(16) float Ws[64][68];
  int b = blockIdx.x / 49;
  int p0 = (blockIdx.x % 49) * 64;
  int o0 = blockIdx.y * 64;
  int tid = threadIdx.x;
  int tx = tid & 15, ty = tid >> 4;
  float acc[4][4] = {};
  for (int cc = 0; cc < Cin; cc += 64) {
    const float* xb = X + ((size_t)b * Cin + cc) * PIX + p0;
#pragma unroll
    for (int i = 0; i < 16; i++) {
      int idx = i * 256 + tid;
      int r = idx >> 6, c2 = idx & 63;
      Xs[r][c2] = xb[(size_t)r * PIX + c2];
    }
#pragma unroll
    for (int i = 0; i < 16; i++) {
      int idx = i * 256 + tid;
      int oi = idx >> 6, ci = idx & 63;
      Ws[ci][oi] = W[(size_t)(o0 + oi) * Cin + cc + ci];
    }
    __syncthreads();
#pragma unroll 8
    for (int k = 0; k < 64; k++) {
      float4 xv = *(const float4*)&Xs[k][tx * 4];
      float4 wv = *(const float4*)&Ws[k][ty * 4];
      float xa[4] = {xv.x, xv.y, xv.z, xv.w};
      float wa[4] = {wv.x, wv.y, wv.z, wv.w};
#pragma unroll
      for (int i = 0; i < 4; i++)
#pragma unroll
        for (int j = 0; j < 4; j++) acc[i][j] += wa[i] * xa[j];
    }
    __syncthreads();
  }
#pragma unroll
  for (int i = 0; i < 4; i++) {
    int o = o0 + ty * 4 + i;
    float bv = bias[o];
#pragma unroll
    for (int j = 0; j < 4; j++) {
      int p = p0 + tx * 4 + j;
      float val = acc[i][j] + bv;
      if (EPI == EPI_ADD) {
        size_t oidx = ((size_t)b * Cout + o) * PIX + p;
        Y[oidx] = val + extra[oidx];
      } else if (EPI == EPI_GELU) {
        Y[((size_t)b * Cout + o) * PIX + p] =
            0.5f * val * (1.f + erff(val * 0.70710678118654752f));
      } else {  // EPI_QKV scatter: o = s*192 + head*32 + ch
        int s = o / CDIM, rr = o - s * CDIM;
        int head = rr >> 5, ch = rr & 31;
        int img = b * NHEADS + head;
        if (s == 0)
          Y[((size_t)img * 64 + ch) * PIX + p] = val;           // q (pre-scaled)
        else if (s == 1)
          Y[((size_t)img * 64 + 32 + ch) * PIX + p] = val;      // k
        else
          Y2[((size_t)img * 32 + ch) * PIX + p] = val;          // v
      }
    }
  }
}

// ---------------- 7x7 conv 64->49 producing attention logits ----------------
__global__ __launch_bounds__(256) void attn_conv_k(const float* __restrict__ qk,
                                                   const float* __restrict__ dm_w,
                                                   const float* __restrict__ dm_b,
                                                   const float* __restrict__ rel_bias,
                                                   float* __restrict__ attnL) {
  __shared__ float patch[64][196];  // 64 ch x 14x14, 50 KB
  int img = blockIdx.x / 49;
  int tile = blockIdx.x % 49;
  int y0 = (tile / 7) * 8, x0 = (tile % 7) * 8;
  int tid = threadIdx.x;
  const float* qki = qk + (size_t)img * 64 * PIX;
  for (int idx = tid; idx < 64 * 196; idx += 256) {
    int ch = idx / 196, rr = idx - ch * 196;
    int r = rr / 14, cc = rr - r * 14;
    int gy = y0 - 3 + r, gx = x0 - 3 + cc;
    patch[ch][rr] = ((unsigned)gy < 56u && (unsigned)gx < 56u)
                        ? qki[(size_t)ch * PIX + gy * 56 + gx] : 0.f;
  }
  __syncthreads();
  int pixel = tid & 63;
  int kg = __builtin_amdgcn_readfirstlane(tid >> 6);  // wave-uniform ko residue
  int px = pixel & 7, py = pixel >> 3;
  int head = img % NHEADS;
  float acc[13];
#pragma unroll
  for (int t = 0; t < 13; t++) {
    int ko = kg + 4 * t;
    acc[t] = (ko < KWIN) ? dm_b[ko] + rel_bias[ko * NHEADS + head] : 0.f;
  }
  for (int ci = 0; ci < 64; ci++) {
    float pv[49];
#pragma unroll
    for (int kh = 0; kh < 7; kh++)
#pragma unroll
      for (int kw = 0; kw < 7; kw++)
        pv[kh * 7 + kw] = patch[ci][(py + kh) * 14 + px + kw];
#pragma unroll
    for (int t = 0; t < 13; t++) {
      int ko = kg + 4 * t;
      if (ko < KWIN) {
        const float* wr = dm_w + (size_t)ko * 3136 + ci * 49;
#pragma unroll
        for (int kk = 0; kk < 49; kk++) acc[t] += wr[kk] * pv[kk];
      }
    }
  }
  int p = (y0 + py) * 56 + x0 + px;
#pragma unroll
  for (int t = 0; t < 13; t++) {
    int ko = kg + 4 * t;
    if (ko < KWIN) attnL[((size_t)img * KWIN + ko) * PIX + p] = acc[t];
  }
}

// ---------------- softmax over 49 + weighted v-patch aggregation ------------
__global__ __launch_bounds__(64) void softagg_k(const float* __restrict__ attnL,
                                                const float* __restrict__ v,
                                                float* __restrict__ attno) {
  __shared__ float vp[32][196];  // 25 KB
  int img = blockIdx.x / 49;
  int tile = blockIdx.x % 49;
  int y0 = (tile / 7) * 8, x0 = (tile % 7) * 8;
  int tid = threadIdx.x;
  const float* vi = v + (size_t)img * 32 * PIX;
  for (int idx = tid; idx < 32 * 196; idx += 64) {
    int ch = idx / 196, rr = idx - ch * 196;
    int r = rr / 14, cc = rr - r * 14;
    int gy = y0 - 3 + r, gx = x0 - 3 + cc;
    vp[ch][rr] = ((unsigned)gy < 56u && (unsigned)gx < 56u)
                     ? vi[(size_t)ch * PIX + gy * 56 + gx] : 0.f;
  }
  __syncthreads();
  int px = tid & 7, py = tid >> 3;
  int p = (y0 + py) * 56 + x0 + px;
  float a[49];
  float m = -1e30f;
#pragma unroll
  for (int k = 0; k < KWIN; k++) {
    a[k] = attnL[((size_t)img * KWIN + k) * PIX + p];
    m = fmaxf(m, a[k]);
  }
  float s = 0.f;
#pragma unroll
  for (int k = 0; k < KWIN; k++) {
    a[k] = __expf(a[k] - m);
    s += a[k];
  }
  float inv = 1.f / s;
  int b = img / NHEADS, head = img % NHEADS;
  float* outb = attno + ((size_t)b * CDIM + head * HDIM) * PIX + p;
  for (int c = 0; c < 32; c++) {
    float accv = 0.f;
#pragma unroll
    for (int kh = 0; kh < 7; kh++)
#pragma unroll
      for (int kw = 0; kw < 7; kw++)
        accv += a[kh * 7 + kw] * vp[c][(py + kh) * 14 + px + kw];
    outb[(size_t)c * PIX] = accv * inv;
  }
}

// ---------------- launch ----------------------------------------------------
extern "C" void kernel_launch(void* const* d_in, const int* in_sizes, int n_in,
                              void* d_out, int out_size, void* d_ws, size_t ws_size,
                              hipStream_t stream) {
  const float* x        = (const float*)d_in[0];
  const float* bn_gamma = (const float*)d_in[1];
  const float* bn_beta  = (const float*)d_in[2];
  const float* qkv_w    = (const float*)d_in[3];
  const float* qkv_b    = (const float*)d_in[4];
  const float* dm_w     = (const float*)d_in[5];
  const float* dm_b     = (const float*)d_in[6];
  const float* rel_bias = (const float*)d_in[7];
  const float* proj_w   = (const float*)d_in[8];
  const float* proj_b   = (const float*)d_in[9];
  const float* c1_w     = (const float*)d_in[10];
  const float* c1_b     = (const float*)d_in[11];
  const float* c2_w     = (const float*)d_in[12];
  const float* c2_b     = (const float*)d_in[13];
  float* out = (float*)d_out;
  float* ws  = (float*)d_ws;

  float* stats = ws;                              // 384
  float* w_eff = ws + 384;                        // 576*192
  float* b_eff = w_eff + 576 * 192;               // 576
  float* qk    = b_eff + 576;                     // 24*64*PIX
  float* vbuf  = qk + (size_t)NIMG * 64 * PIX;    // 24*32*PIX
  float* attnL = vbuf + (size_t)NIMG * 32 * PIX;  // 24*49*PIX
  float* attno = attnL + (size_t)NIMG * KWIN * PIX;  // 4*192*PIX
  float* x1    = attno + (size_t)BATCH * CDIM * PIX; // 4*192*PIX
  float* hbuf  = qk;  // alias: 4*768*PIX fits in dead qk+v+attnL region

  bn_stats_k<<<CDIM, 256, 0, stream>>>(x, stats);
  fold_k<<<576, 192, 0, stream>>>(qkv_w, qkv_b, bn_gamma, bn_beta, stats, w_eff, b_eff);
  gemm_k<EPI_QKV><<<dim3(BATCH * 49, 9), 256, 0, stream>>>(
      x, w_eff, b_eff, qk, nullptr, vbuf, 192, 576);
  attn_conv_k<<<NIMG * 49, 256, 0, stream>>>(qk, dm_w, dm_b, rel_bias, attnL);
  softagg_k<<<NIMG * 49, 64, 0, stream>>>(attnL, vbuf, attno);
  gemm_k<EPI_ADD><<<dim3(BATCH * 49, 3), 256, 0, stream>>>(
      attno, proj_w, proj_b, x1, x, nullptr, 192, 192);
  gemm_k<EPI_GELU><<<dim3(BATCH * 49, 12), 256, 0, stream>>>(
      x1, c1_w, c1_b, hbuf, nullptr, nullptr, 192, 768);
  gemm_k<EPI_ADD><<<dim3(BATCH * 49, 3), 256, 0, stream>>>(
      hbuf, c2_w, c2_b, out, x1, nullptr, 768, 192);
}

// Round 2
// 491.404 us; speedup vs baseline: 2.3801x; 2.3801x over previous
//
#include <hip/hip_runtime.h>
#include <hip/hip_bf16.h>
#include <math.h>

#define CDIM 192
#define NHEADS 6
#define HDIM 32
#define WIN 7
#define KWIN 49
#define BATCH 4
#define PIX 3136      // 56*56
#define NIMG 24       // BATCH*NHEADS
#define EPSV 1e-5f

typedef __bf16 bf16x8 __attribute__((ext_vector_type(8)));
typedef float f32x16 __attribute__((ext_vector_type(16)));
typedef unsigned int uint4v __attribute__((ext_vector_type(4)));

// ---------------- BN stats: per-channel mean / inv_std over (B,H,W) ----------
__global__ __launch_bounds__(256) void bn_stats_k(const float* __restrict__ x,
                                                  float* __restrict__ stats) {
  int c = blockIdx.x;
  float s = 0.f, q = 0.f;
  for (int n = threadIdx.x; n < BATCH * PIX; n += 256) {
    int b = n / PIX, p = n - b * PIX;
    float v = x[((size_t)b * CDIM + c) * PIX + p];
    s += v; q += v * v;
  }
  __shared__ float rs[256], rq[256];
  rs[threadIdx.x] = s; rq[threadIdx.x] = q;
  __syncthreads();
  for (int st = 128; st > 0; st >>= 1) {
    if (threadIdx.x < st) { rs[threadIdx.x] += rs[threadIdx.x + st]; rq[threadIdx.x] += rq[threadIdx.x + st]; }
    __syncthreads();
  }
  if (threadIdx.x == 0) {
    float mean = rs[0] / (float)(BATCH * PIX);
    float var = rq[0] / (float)(BATCH * PIX) - mean * mean;
    stats[c] = mean;
    stats[CDIM + c] = rsqrtf(var + EPSV);
  }
}

// ---------------- fold BN (and q-scale) into qkv weights --------------------
__global__ __launch_bounds__(192) void fold_k(const float* __restrict__ qkv_w,
                                              const float* __restrict__ qkv_b,
                                              const float* __restrict__ gamma,
                                              const float* __restrict__ beta,
                                              const float* __restrict__ stats,
                                              float* __restrict__ w_eff,
                                              float* __restrict__ b_eff) {
  int o = blockIdx.x, c = threadIdx.x;
  float alpha = gamma[c] * stats[CDIM + c];
  float shift = beta[c] - stats[c] * alpha;
  float w = qkv_w[o * CDIM + c];
  float scale = (o < CDIM) ? 0.17677669529663687f : 1.f;  // HD^-0.5 on q rows
  w_eff[o * CDIM + c] = w * alpha * scale;
  __shared__ float r[CDIM];
  r[c] = w * shift;
  __syncthreads();
  if (c == 0) {
    float s = 0.f;
    for (int i = 0; i < CDIM; i++) s += r[i];
    b_eff[o] = (qkv_b[o] + s) * scale;
  }
}

// ---------------- pack dm_w into MFMA-fragment-major bf16 -------------------
// wTb2 elem idx = (((Mt*49+tap)*4 + ch)*64 + lane)*8 + e
// ko = Mt*32 + (lane&31), ci = ch*16 + (lane>>5)*8 + e  (ko>=49 rows are zero)
__global__ __launch_bounds__(256) void wprep_k(const float* __restrict__ dm_w,
                                               __hip_bfloat16* __restrict__ wTb2) {
  int idx = blockIdx.x * 256 + threadIdx.x;
  if (idx >= 200704) return;
  int e = idx & 7;
  int tmp = idx >> 3;
  int lane = tmp & 63; tmp >>= 6;
  int ch = tmp & 3; tmp >>= 2;
  int tap = tmp % 49, Mt = tmp / 49;
  int ko = Mt * 32 + (lane & 31);
  int ci = ch * 16 + (lane >> 5) * 8 + e;
  float v = (ko < KWIN) ? dm_w[(size_t)ko * 3136 + ci * 49 + tap] : 0.f;
  wTb2[idx] = __float2bfloat16(v);
}

// ---------------- tiled fp32 1x1-conv GEMM: Y[b,o,p] = sum_c W[o,c] X[b,c,p] -
#define EPI_QKV 0
#define EPI_ADD 1
#define EPI_GELU 2

template <int EPI>
__global__ __launch_bounds__(256) void gemm_k(const float* __restrict__ X,
                                              const float* __restrict__ W,
                                              const float* __restrict__ bias,
                                              float* __restrict__ Y,
                                              const float* __restrict__ extra,
                                              float* __restrict__ Y2,
                                              int Cin, int Cout) {
  __shared__ __align__(16) float Xs[64][68];
  __shared__ __align__(16) float Ws[64][68];
  int b = blockIdx.x / 49;
  int p0 = (blockIdx.x % 49) * 64;
  int o0 = blockIdx.y * 64;
  int tid = threadIdx.x;
  int tx = tid & 15, ty = tid >> 4;
  float acc[4][4] = {};
  for (int cc = 0; cc < Cin; cc += 64) {
    const float* xb = X + ((size_t)b * Cin + cc) * PIX + p0;
#pragma unroll
    for (int i = 0; i < 16; i++) {
      int idx = i * 256 + tid;
      int r = idx >> 6, c2 = idx & 63;
      Xs[r][c2] = xb[(size_t)r * PIX + c2];
    }
#pragma unroll
    for (int i = 0; i < 16; i++) {
      int idx = i * 256 + tid;
      int oi = idx >> 6, ci = idx & 63;
      Ws[ci][oi] = W[(size_t)(o0 + oi) * Cin + cc + ci];
    }
    __syncthreads();
#pragma unroll 8
    for (int k = 0; k < 64; k++) {
      float4 xv = *(const float4*)&Xs[k][tx * 4];
      float4 wv = *(const float4*)&Ws[k][ty * 4];
      float xa[4] = {xv.x, xv.y, xv.z, xv.w};
      float wa[4] = {wv.x, wv.y, wv.z, wv.w};
#pragma unroll
      for (int i = 0; i < 4; i++)
#pragma unroll
        for (int j = 0; j < 4; j++) acc[i][j] += wa[i] * xa[j];
    }
    __syncthreads();
  }
#pragma unroll
  for (int i = 0; i < 4; i++) {
    int o = o0 + ty * 4 + i;
    float bv = bias[o];
#pragma unroll
    for (int j = 0; j < 4; j++) {
      int p = p0 + tx * 4 + j;
      float val = acc[i][j] + bv;
      if (EPI == EPI_ADD) {
        size_t oidx = ((size_t)b * Cout + o) * PIX + p;
        Y[oidx] = val + extra[oidx];
      } else if (EPI == EPI_GELU) {
        Y[((size_t)b * Cout + o) * PIX + p] =
            0.5f * val * (1.f + erff(val * 0.70710678118654752f));
      } else {  // EPI_QKV: q,k -> bf16 qkT[img][pix][64]; v -> fp32 [img][32][PIX]
        int s = o / CDIM, rr = o - s * CDIM;
        int head = rr >> 5, ch = rr & 31;
        int img = b * NHEADS + head;
        if (s == 2)
          Y2[((size_t)img * 32 + ch) * PIX + p] = val;
        else
          ((__hip_bfloat16*)Y)[((size_t)img * PIX + p) * 64 + s * 32 + ch] =
              __float2bfloat16(val);
      }
    }
  }
}

// ---------------- 7x7 attn conv via implicit-GEMM MFMA ----------------------
// out[img][ko][p] = sum_{ci,kh,kw} w[ko][ci][kh][kw]*qk[ci][y+kh-3][x+kw-3]
__global__ __launch_bounds__(256) void attn_mfma_k(const unsigned short* __restrict__ qkT,
                                                   const unsigned short* __restrict__ wTb2,
                                                   const float* __restrict__ dm_b,
                                                   const float* __restrict__ rel_bias,
                                                   float* __restrict__ attnL) {
  __shared__ __align__(16) unsigned short patch[196 * 64];  // 25 KB, [pix][ci] swizzled
  int img = blockIdx.x / 49;
  int tile = blockIdx.x % 49;
  int y0 = (tile / 7) * 8, x0 = (tile % 7) * 8;
  int tid = threadIdx.x;

  // stage 14x14x64ch bf16 patch; granule g (8 ci) stored at slot g^(pix&7)
  const unsigned short* qbase = qkT + (size_t)img * PIX * 64;
  for (int idx = tid; idx < 1568; idx += 256) {
    int pix = idx >> 3, g = idx & 7;
    int r = pix / 14, c = pix - r * 14;
    int gy = y0 - 3 + r, gx = x0 - 3 + c;
    uint4v val = {0u, 0u, 0u, 0u};
    if ((unsigned)gy < 56u && (unsigned)gx < 56u)
      val = *(const uint4v*)(qbase + (size_t)(gy * 56 + gx) * 64 + g * 8);
    *(uint4v*)&patch[pix * 64 + ((g ^ (pix & 7)) << 3)] = val;
  }
  __syncthreads();

  int lane = tid & 63, wid = tid >> 6;
  int Mtile = wid & 1, Ntile = wid >> 1;
  int n = lane & 31, kgrp = lane >> 5;
  int py = Ntile * 4 + (n >> 3), px = n & 7;
  f32x16 acc;
#pragma unroll
  for (int i = 0; i < 16; i++) acc[i] = 0.f;

  const unsigned short* Abase = wTb2 + (size_t)Mtile * 49 * 4 * 512 + lane * 8;
#pragma unroll
  for (int kh = 0; kh < 7; kh++) {
#pragma unroll
    for (int kw = 0; kw < 7; kw++) {
      int tap = kh * 7 + kw;
      int lp = (py + kh) * 14 + px + kw;
      int lpand = lp & 7;
#pragma unroll
      for (int ch = 0; ch < 4; ch++) {
        bf16x8 a = __builtin_bit_cast(bf16x8,
            *(const uint4v*)(Abase + (size_t)(tap * 4 + ch) * 512));
        int g = ch * 2 + kgrp;
        bf16x8 bb = __builtin_bit_cast(bf16x8,
            *(const uint4v*)&patch[lp * 64 + ((g ^ lpand) << 3)]);
        acc = __builtin_amdgcn_mfma_f32_32x32x16_bf16(a, bb, acc, 0, 0, 0);
      }
    }
  }

  // epilogue: C col=lane&31 (pixel), row=(r&3)+8*(r>>2)+4*(lane>>5) (ko in tile)
  int head = img % NHEADS;
  int pout = (y0 + Ntile * 4 + (n >> 3)) * 56 + x0 + (n & 7);
  float* outb = attnL + (size_t)img * KWIN * PIX + pout;
#pragma unroll
  for (int r = 0; r < 16; r++) {
    int ko = Mtile * 32 + (r & 3) + 8 * (r >> 2) + 4 * kgrp;
    if (ko < KWIN)
      outb[(size_t)ko * PIX] = acc[r] + dm_b[ko] + rel_bias[ko * NHEADS + head];
  }
}

// ---------------- softmax over 49 + weighted v-patch aggregation ------------
__global__ __launch_bounds__(64) void softagg_k(const float* __restrict__ attnL,
                                                const float* __restrict__ v,
                                                float* __restrict__ attno) {
  __shared__ float vp[32][196];  // 25 KB
  int img = blockIdx.x / 49;
  int tile = blockIdx.x % 49;
  int y0 = (tile / 7) * 8, x0 = (tile % 7) * 8;
  int tid = threadIdx.x;
  const float* vi = v + (size_t)img * 32 * PIX;
  for (int idx = tid; idx < 32 * 196; idx += 64) {
    int ch = idx / 196, rr = idx - ch * 196;
    int r = rr / 14, cc = rr - r * 14;
    int gy = y0 - 3 + r, gx = x0 - 3 + cc;
    vp[ch][rr] = ((unsigned)gy < 56u && (unsigned)gx < 56u)
                     ? vi[(size_t)ch * PIX + gy * 56 + gx] : 0.f;
  }
  __syncthreads();
  int px = tid & 7, py = tid >> 3;
  int p = (y0 + py) * 56 + x0 + px;
  float a[49];
  float m = -1e30f;
#pragma unroll
  for (int k = 0; k < KWIN; k++) {
    a[k] = attnL[((size_t)img * KWIN + k) * PIX + p];
    m = fmaxf(m, a[k]);
  }
  float s = 0.f;
#pragma unroll
  for (int k = 0; k < KWIN; k++) {
    a[k] = __expf(a[k] - m);
    s += a[k];
  }
  float inv = 1.f / s;
  int b = img / NHEADS, head = img % NHEADS;
  float* outb = attno + ((size_t)b * CDIM + head * HDIM) * PIX + p;
  for (int c = 0; c < 32; c++) {
    float accv = 0.f;
#pragma unroll
    for (int kh = 0; kh < 7; kh++)
#pragma unroll
      for (int kw = 0; kw < 7; kw++)
        accv += a[kh * 7 + kw] * vp[c][(py + kh) * 14 + px + kw];
    outb[(size_t)c * PIX] = accv * inv;
  }
}

// ---------------- launch ----------------------------------------------------
extern "C" void kernel_launch(void* const* d_in, const int* in_sizes, int n_in,
                              void* d_out, int out_size, void* d_ws, size_t ws_size,
                              hipStream_t stream) {
  const float* x        = (const float*)d_in[0];
  const float* bn_gamma = (const float*)d_in[1];
  const float* bn_beta  = (const float*)d_in[2];
  const float* qkv_w    = (const float*)d_in[3];
  const float* qkv_b    = (const float*)d_in[4];
  const float* dm_w     = (const float*)d_in[5];
  const float* dm_b     = (const float*)d_in[6];
  const float* rel_bias = (const float*)d_in[7];
  const float* proj_w   = (const float*)d_in[8];
  const float* proj_b   = (const float*)d_in[9];
  const float* c1_w     = (const float*)d_in[10];
  const float* c1_b     = (const float*)d_in[11];
  const float* c2_w     = (const float*)d_in[12];
  const float* c2_b     = (const float*)d_in[13];
  float* out = (float*)d_out;
  float* ws  = (float*)d_ws;

  float* stats = ws;                               // 384
  float* w_eff = ws + 384;                         // 576*192 = 110592
  float* b_eff = w_eff + 110592;                   // 576
  float* qkT_f = b_eff + 576;                      // bf16 24*3136*64 = 2408448 floats
  float* vbuf  = qkT_f + 2408448;                  // fp32 24*32*3136 = 2408448
  float* wTb2_f= vbuf + 2408448;                   // bf16 200704 = 100352 floats
  float* attnL = wTb2_f + 100352;                  // 24*49*3136 = 3687936
  float* attno = attnL + 3687936;                  // 4*192*3136 = 2408448
  float* x1    = attno + 2408448;                  // 2408448
  float* hbuf  = qkT_f;  // alias: 4*768*3136 = 9633792 floats, fits in dead qkT..attno

  bn_stats_k<<<CDIM, 256, 0, stream>>>(x, stats);
  fold_k<<<576, 192, 0, stream>>>(qkv_w, qkv_b, bn_gamma, bn_beta, stats, w_eff, b_eff);
  wprep_k<<<784, 256, 0, stream>>>(dm_w, (__hip_bfloat16*)wTb2_f);
  gemm_k<EPI_QKV><<<dim3(BATCH * 49, 9), 256, 0, stream>>>(
      x, w_eff, b_eff, qkT_f, nullptr, vbuf, 192, 576);
  attn_mfma_k<<<NIMG * 49, 256, 0, stream>>>(
      (const unsigned short*)qkT_f, (const unsigned short*)wTb2_f, dm_b, rel_bias, attnL);
  softagg_k<<<NIMG * 49, 64, 0, stream>>>(attnL, vbuf, attno);
  gemm_k<EPI_ADD><<<dim3(BATCH * 49, 3), 256, 0, stream>>>(
      attno, proj_w, proj_b, x1, x, nullptr, 192, 192);
  gemm_k<EPI_GELU><<<dim3(BATCH * 49, 12), 256, 0, stream>>>(
      x1, c1_w, c1_b, hbuf, nullptr, nullptr, 192, 768);
  gemm_k<EPI_ADD><<<dim3(BATCH * 49, 3), 256, 0, stream>>>(
      hbuf, c2_w, c2_b, out, x1, nullptr, 768, 192);
}

// Round 3
// 194.097 us; speedup vs baseline: 6.0259x; 2.5317x over previous
//
#include <hip/hip_runtime.h>
#include <hip/hip_bf16.h>
#include <math.h>

#define CDIM 192
#define NHEADS 6
#define WIN 7
#define KWIN 49
#define BATCH 4
#define PIX 3136      // 56*56
#define NPIX 12544    // BATCH*PIX
#define NIMG 24       // BATCH*NHEADS
#define EPSV 1e-5f

typedef __bf16 bf16x8 __attribute__((ext_vector_type(8)));
typedef float f32x16 __attribute__((ext_vector_type(16)));
typedef unsigned int uint4v __attribute__((ext_vector_type(4)));
typedef unsigned short u16;

// ---------------- BN stats ---------------------------------------------------
__global__ __launch_bounds__(256) void bn_stats_k(const float* __restrict__ x,
                                                  float* __restrict__ stats) {
  int c = blockIdx.x;
  float s = 0.f, q = 0.f;
  for (int n = threadIdx.x; n < BATCH * PIX; n += 256) {
    int b = n / PIX, p = n - b * PIX;
    float v = x[((size_t)b * CDIM + c) * PIX + p];
    s += v; q += v * v;
  }
  __shared__ float rs[256], rq[256];
  rs[threadIdx.x] = s; rq[threadIdx.x] = q;
  __syncthreads();
  for (int st = 128; st > 0; st >>= 1) {
    if (threadIdx.x < st) { rs[threadIdx.x] += rs[threadIdx.x + st]; rq[threadIdx.x] += rq[threadIdx.x + st]; }
    __syncthreads();
  }
  if (threadIdx.x == 0) {
    float mean = rs[0] / (float)(BATCH * PIX);
    float var = rq[0] / (float)(BATCH * PIX) - mean * mean;
    stats[c] = mean;
    stats[CDIM + c] = rsqrtf(var + EPSV);
  }
}

// ---------------- fold BN + q-scale into qkv weights ------------------------
__global__ __launch_bounds__(192) void fold_k(const float* __restrict__ qkv_w,
                                              const float* __restrict__ qkv_b,
                                              const float* __restrict__ gamma,
                                              const float* __restrict__ beta,
                                              const float* __restrict__ stats,
                                              float* __restrict__ w_eff,
                                              float* __restrict__ b_eff) {
  int o = blockIdx.x, c = threadIdx.x;
  float alpha = gamma[c] * stats[CDIM + c];
  float shift = beta[c] - stats[c] * alpha;
  float w = qkv_w[o * CDIM + c];
  float scale = (o < CDIM) ? 0.17677669529663687f : 1.f;
  w_eff[o * CDIM + c] = w * alpha * scale;
  __shared__ float r[CDIM];
  r[c] = w * shift;
  __syncthreads();
  if (c == 0) {
    float s = 0.f;
    for (int i = 0; i < CDIM; i++) s += r[i];
    b_eff[o] = (qkv_b[o] + s) * scale;
  }
}

// ---------------- pack dm_w (attn conv weights) frag-major ------------------
__global__ __launch_bounds__(256) void wprep_k(const float* __restrict__ dm_w,
                                               __hip_bfloat16* __restrict__ wTb2) {
  int idx = blockIdx.x * 256 + threadIdx.x;
  if (idx >= 200704) return;
  int e = idx & 7;
  int tmp = idx >> 3;
  int lane = tmp & 63; tmp >>= 6;
  int ch = tmp & 3; tmp >>= 2;
  int tap = tmp % 49, Mt = tmp / 49;
  int ko = Mt * 32 + (lane & 31);
  int ci = ch * 16 + (lane >> 5) * 8 + e;
  float v = (ko < KWIN) ? dm_w[(size_t)ko * 3136 + ci * 49 + tap] : 0.f;
  wTb2[idx] = __float2bfloat16(v);
}

// ---------------- generic GEMM weight pack: W[Cout][Cin] -> frag-major ------
__global__ __launch_bounds__(256) void pack_k(const float* __restrict__ W,
                                              u16* __restrict__ out,
                                              int Cin, int total8) {
  int t = blockIdx.x * 256 + threadIdx.x;
  if (t >= total8) return;
  int lane = t & 63, rest = t >> 6;
  int nK = Cin >> 4;
  int kk = rest % nK, mtg = rest / nK;
  int o = mtg * 32 + (lane & 31), c = kk * 16 + (lane >> 5) * 8;
  const float* src = W + (size_t)o * Cin + c;
  __hip_bfloat16 tmp[8];
#pragma unroll
  for (int e = 0; e < 8; e++) tmp[e] = __float2bfloat16(src[e]);
  *(uint4v*)(out + (size_t)t * 8) = *(uint4v*)tmp;
}

// ---------------- x [b][c][p] fp32 -> xT [b*p][192] bf16 --------------------
__global__ __launch_bounds__(256) void xT_k(const float* __restrict__ x,
                                            u16* __restrict__ xT) {
  __shared__ float Ls[64][33];
  int bb = blockIdx.x / 49;
  int p0 = (blockIdx.x % 49) * 64;
  int c0 = blockIdx.y * 32;
  int tid = threadIdx.x;
  int j = tid & 63;
#pragma unroll
  for (int it = 0; it < 8; it++) {
    int c = it * 4 + (tid >> 6);
    Ls[j][c] = x[((size_t)bb * CDIM + c0 + c) * PIX + p0 + j];
  }
  __syncthreads();
  int jr = tid >> 2, t = tid & 3;
  __hip_bfloat16 tmp[8];
#pragma unroll
  for (int u = 0; u < 8; u++) tmp[u] = __float2bfloat16(Ls[jr][t * 8 + u]);
  *(uint4v*)(xT + (size_t)(bb * PIX + p0 + jr) * CDIM + c0 + t * 8) = *(uint4v*)tmp;
}

// ---------------- MFMA GEMM: Y[o][gp] = sum_c W[o][c] * Bm[gp][c] -----------
// Bm: [NPIX][Cin] bf16 pixel-major. Apk: frag-major packed weights.
#define MG_QKV 0
#define MG_PROJ 1
#define MG_GELU 2
#define MG_C2 3

template <int EPI>
__global__ __launch_bounds__(256) void mgemm_k(
    const u16* __restrict__ Bm, const u16* __restrict__ Apk,
    const float* __restrict__ bias,
    float* __restrict__ outF, u16* __restrict__ outT,
    const float* __restrict__ extra, int Cin) {
  __shared__ __align__(16) u16 Bs[256 * 64];  // 32 KB, swizzled
  int tid = threadIdx.x;
  int lane = tid & 63, wid = tid >> 6;
  int hi = lane >> 5, ln31 = lane & 31;
  int p0 = blockIdx.x * 256;
  int o0 = blockIdx.y * 64;
  int nK = Cin >> 4;
  f32x16 acc[2][2];
#pragma unroll
  for (int mt = 0; mt < 2; mt++)
#pragma unroll
    for (int nt = 0; nt < 2; nt++)
#pragma unroll
      for (int i = 0; i < 16; i++) acc[mt][nt][i] = 0.f;

  for (int cc = 0; cc < Cin; cc += 64) {
#pragma unroll
    for (int i = 0; i < 8; i++) {
      int idx = i * 256 + tid;
      int p = idx >> 3, g = idx & 7;
      uint4v v = *(const uint4v*)(Bm + (size_t)(p0 + p) * Cin + cc + g * 8);
      *(uint4v*)&Bs[p * 64 + ((g ^ (p & 7)) << 3)] = v;
    }
    __syncthreads();
    const u16* Ab = Apk + ((size_t)(o0 >> 5) * nK + (cc >> 4)) * 512 + lane * 8;
    int pA = wid * 64 + ln31;
    int pB = pA + 32;
    int sw = pA & 7;
#pragma unroll
    for (int ks = 0; ks < 4; ks++) {
      int g = ks * 2 + hi;
      bf16x8 b0 = *(const bf16x8*)&Bs[pA * 64 + ((g ^ sw) << 3)];
      bf16x8 b1 = *(const bf16x8*)&Bs[pB * 64 + ((g ^ sw) << 3)];
      bf16x8 a0 = *(const bf16x8*)(Ab + ks * 512);
      bf16x8 a1 = *(const bf16x8*)(Ab + (nK + ks) * 512);
      acc[0][0] = __builtin_amdgcn_mfma_f32_32x32x16_bf16(a0, b0, acc[0][0], 0, 0, 0);
      acc[0][1] = __builtin_amdgcn_mfma_f32_32x32x16_bf16(a0, b1, acc[0][1], 0, 0, 0);
      acc[1][0] = __builtin_amdgcn_mfma_f32_32x32x16_bf16(a1, b0, acc[1][0], 0, 0, 0);
      acc[1][1] = __builtin_amdgcn_mfma_f32_32x32x16_bf16(a1, b1, acc[1][1], 0, 0, 0);
    }
    __syncthreads();
  }

  // ---- epilogue ----
  if (EPI == MG_C2 || (EPI == MG_QKV && o0 >= 384)) {
    // reg-direct fp32 writes (coalesced: fixed reg -> 32 consecutive pixels)
#pragma unroll
    for (int mt = 0; mt < 2; mt++)
#pragma unroll
      for (int r = 0; r < 16; r++) {
        int o = o0 + mt * 32 + (r & 3) + 8 * (r >> 2) + 4 * hi;
        float bv = bias[o];
#pragma unroll
        for (int nt = 0; nt < 2; nt++) {
          unsigned gp = p0 + wid * 64 + nt * 32 + ln31;
          unsigned bb = gp / PIX, pp = gp - bb * PIX;
          if (EPI == MG_C2) {
            size_t oi = ((size_t)bb * CDIM + o) * PIX + pp;
            outF[oi] = acc[mt][nt][r] + bv + extra[oi];
          } else {  // v
            int ch = o - 384;
            outF[((size_t)(bb * NHEADS + (ch >> 5)) * 32 + (ch & 31)) * PIX + pp] =
                acc[mt][nt][r] + bv;
          }
        }
      }
  } else {
    // bf16-transposed output via wave-local LDS transpose
#pragma unroll
    for (int mt = 0; mt < 2; mt++)
#pragma unroll
      for (int r = 0; r < 16; r++) {
        int o_loc = mt * 32 + (r & 3) + 8 * (r >> 2) + 4 * hi;
        int o = o0 + o_loc;
        float bv = bias[o];
#pragma unroll
        for (int nt = 0; nt < 2; nt++) {
          int p_loc = wid * 64 + nt * 32 + ln31;
          float val = acc[mt][nt][r] + bv;
          if (EPI == MG_PROJ) {
            unsigned gp = p0 + p_loc;
            unsigned bb = gp / PIX, pp = gp - bb * PIX;
            size_t oi = ((size_t)bb * CDIM + o) * PIX + pp;
            val += extra[oi];
            outF[oi] = val;
          }
          if (EPI == MG_GELU)
            val = 0.5f * val * (1.f + erff(val * 0.70710678118654752f));
          *(__hip_bfloat16*)&Bs[p_loc * 64 + (((o_loc >> 3) ^ (p_loc & 7)) << 3) + (o_loc & 7)] =
              __float2bfloat16(val);
        }
      }
    int prow = wid * 64 + lane;
    int psw = prow & 7;
    uint4v r8[8];
#pragma unroll
    for (int g = 0; g < 8; g++)
      r8[g] = *(const uint4v*)&Bs[prow * 64 + ((g ^ psw) << 3)];
    unsigned gp = p0 + prow;
    if (EPI == MG_QKV) {
      unsigned bb = gp / PIX, pp = gp - bb * PIX;
      int s = (o0 >= 192) ? 1 : 0;
      int h0 = (o0 - s * 192) >> 5;
      u16* d0 = outT + ((size_t)(bb * NHEADS + h0) * PIX + pp) * 64 + s * 32;
      u16* d1 = outT + ((size_t)(bb * NHEADS + h0 + 1) * PIX + pp) * 64 + s * 32;
      *(uint4v*)(d0) = r8[0]; *(uint4v*)(d0 + 8) = r8[1];
      *(uint4v*)(d0 + 16) = r8[2]; *(uint4v*)(d0 + 24) = r8[3];
      *(uint4v*)(d1) = r8[4]; *(uint4v*)(d1 + 8) = r8[5];
      *(uint4v*)(d1 + 16) = r8[6]; *(uint4v*)(d1 + 24) = r8[7];
    } else if (EPI == MG_PROJ) {
      u16* d = outT + (size_t)gp * CDIM + o0;
#pragma unroll
      for (int g = 0; g < 8; g++) *(uint4v*)(d + g * 8) = r8[g];
    } else {  // GELU -> hT [gp][768]
      u16* d = outT + (size_t)gp * 768 + o0;
#pragma unroll
      for (int g = 0; g < 8; g++) *(uint4v*)(d + g * 8) = r8[g];
    }
  }
}

// ---------------- 7x7 attn conv via implicit-GEMM MFMA ----------------------
__global__ __launch_bounds__(256) void attn_mfma_k(const u16* __restrict__ qkT,
                                                   const u16* __restrict__ wTb2,
                                                   const float* __restrict__ dm_b,
                                                   const float* __restrict__ rel_bias,
                                                   float* __restrict__ attnL) {
  __shared__ __align__(16) u16 patch[196 * 64];
  int img = blockIdx.x / 49;
  int tile = blockIdx.x % 49;
  int y0 = (tile / 7) * 8, x0 = (tile % 7) * 8;
  int tid = threadIdx.x;
  const u16* qbase = qkT + (size_t)img * PIX * 64;
  for (int idx = tid; idx < 1568; idx += 256) {
    int pix = idx >> 3, g = idx & 7;
    int r = pix / 14, c = pix - r * 14;
    int gy = y0 - 3 + r, gx = x0 - 3 + c;
    uint4v val = {0u, 0u, 0u, 0u};
    if ((unsigned)gy < 56u && (unsigned)gx < 56u)
      val = *(const uint4v*)(qbase + (size_t)(gy * 56 + gx) * 64 + g * 8);
    *(uint4v*)&patch[pix * 64 + ((g ^ (pix & 7)) << 3)] = val;
  }
  __syncthreads();

  int lane = tid & 63, wid = tid >> 6;
  int Mtile = wid & 1, Ntile = wid >> 1;
  int n = lane & 31, kgrp = lane >> 5;
  int py = Ntile * 4 + (n >> 3), px = n & 7;
  f32x16 acc;
#pragma unroll
  for (int i = 0; i < 16; i++) acc[i] = 0.f;

  const u16* Abase = wTb2 + (size_t)Mtile * 49 * 4 * 512 + lane * 8;
#pragma unroll
  for (int kh = 0; kh < 7; kh++) {
#pragma unroll
    for (int kw = 0; kw < 7; kw++) {
      int tap = kh * 7 + kw;
      int lp = (py + kh) * 14 + px + kw;
      int lpand = lp & 7;
#pragma unroll
      for (int ch = 0; ch < 4; ch++) {
        bf16x8 a = __builtin_bit_cast(bf16x8,
            *(const uint4v*)(Abase + (size_t)(tap * 4 + ch) * 512));
        int g = ch * 2 + kgrp;
        bf16x8 bb = __builtin_bit_cast(bf16x8,
            *(const uint4v*)&patch[lp * 64 + ((g ^ lpand) << 3)]);
        acc = __builtin_amdgcn_mfma_f32_32x32x16_bf16(a, bb, acc, 0, 0, 0);
      }
    }
  }

  int head = img % NHEADS;
  int pout = (y0 + Ntile * 4 + (n >> 3)) * 56 + x0 + (n & 7);
  float* outb = attnL + (size_t)img * KWIN * PIX + pout;
#pragma unroll
  for (int r = 0; r < 16; r++) {
    int ko = Mtile * 32 + (r & 3) + 8 * (r >> 2) + 4 * kgrp;
    if (ko < KWIN)
      outb[(size_t)ko * PIX] = acc[r] + dm_b[ko] + rel_bias[ko * NHEADS + head];
  }
}

// ---------------- softmax(49) + v-patch aggregation -> attnoT bf16 ----------
__global__ __launch_bounds__(256) void softagg_k(const float* __restrict__ attnL,
                                                 const float* __restrict__ v,
                                                 u16* __restrict__ attnoT) {
  __shared__ float vp[32][196];
  int img = blockIdx.x / 49, tile = blockIdx.x % 49;
  int y0 = (tile / 7) * 8, x0 = (tile % 7) * 8;
  int tid = threadIdx.x;
  const float* vi = v + (size_t)img * 32 * PIX;
  for (int idx = tid; idx < 32 * 196; idx += 256) {
    int ch = idx / 196, rr = idx - ch * 196;
    int r = rr / 14, cc2 = rr - r * 14;
    int gy = y0 - 3 + r, gx = x0 - 3 + cc2;
    vp[ch][rr] = ((unsigned)gy < 56u && (unsigned)gx < 56u)
                     ? vi[(size_t)ch * PIX + gy * 56 + gx] : 0.f;
  }
  __syncthreads();
  int px = tid & 7, py = (tid >> 3) & 7, cq = tid >> 6;
  int p = (y0 + py) * 56 + x0 + px;
  const float* al = attnL + (size_t)img * KWIN * PIX + p;
  float a[49];
  float m = -1e30f;
#pragma unroll
  for (int k = 0; k < KWIN; k++) { a[k] = al[(size_t)k * PIX]; m = fmaxf(m, a[k]); }
  float s = 0.f;
#pragma unroll
  for (int k = 0; k < KWIN; k++) { a[k] = __expf(a[k] - m); s += a[k]; }
  float inv = 1.f / s;
  int b = img / NHEADS, head = img % NHEADS;
  __hip_bfloat16 ob[8];
#pragma unroll
  for (int c8 = 0; c8 < 8; c8++) {
    int c = cq * 8 + c8;
    float accv = 0.f;
#pragma unroll
    for (int kh = 0; kh < 7; kh++)
#pragma unroll
      for (int kw = 0; kw < 7; kw++)
        accv += a[kh * 7 + kw] * vp[c][(py + kh) * 14 + px + kw];
    ob[c8] = __float2bfloat16(accv * inv);
  }
  *(uint4v*)(attnoT + ((size_t)b * PIX + p) * CDIM + head * 32 + cq * 8) = *(uint4v*)ob;
}

// ---------------- launch ----------------------------------------------------
extern "C" void kernel_launch(void* const* d_in, const int* in_sizes, int n_in,
                              void* d_out, int out_size, void* d_ws, size_t ws_size,
                              hipStream_t stream) {
  const float* x        = (const float*)d_in[0];
  const float* bn_gamma = (const float*)d_in[1];
  const float* bn_beta  = (const float*)d_in[2];
  const float* qkv_w    = (const float*)d_in[3];
  const float* qkv_b    = (const float*)d_in[4];
  const float* dm_w     = (const float*)d_in[5];
  const float* dm_b     = (const float*)d_in[6];
  const float* rel_bias = (const float*)d_in[7];
  const float* proj_w   = (const float*)d_in[8];
  const float* proj_b   = (const float*)d_in[9];
  const float* c1_w     = (const float*)d_in[10];
  const float* c1_b     = (const float*)d_in[11];
  const float* c2_w     = (const float*)d_in[12];
  const float* c2_b     = (const float*)d_in[13];
  float* out = (float*)d_out;
  float* ws  = (float*)d_ws;

  float* stats   = ws;
  float* w_eff   = stats + 384;
  float* b_eff   = w_eff + 110592;
  u16*   pk_qkv  = (u16*)(b_eff + 576);      // 110592 u16
  u16*   pk_proj = pk_qkv + 110592;          // 36864
  u16*   pk_c1   = pk_proj + 36864;          // 147456
  u16*   pk_c2   = pk_c1 + 147456;           // 147456
  u16*   wTb2    = pk_c2 + 147456;           // 200704
  u16*   xT      = wTb2 + 200704;            // 2408448 u16
  u16*   qkT     = xT + 2408448;             // 4816896 u16
  float* vbuf    = (float*)(qkT + 4816896);  // 2408448 f
  float* attnL   = vbuf + 2408448;           // 3687936 f
  u16*   attnoT  = (u16*)(attnL + 3687936);  // 2408448 u16
  float* x1      = (float*)(attnoT + 2408448);  // 2408448 f
  u16*   x1T     = (u16*)(x1 + 2408448);     // 2408448 u16
  u16*   hT      = xT;  // alias: 9633792 u16 over dead xT+qkT+vbuf (12M u16)

  bn_stats_k<<<CDIM, 256, 0, stream>>>(x, stats);
  fold_k<<<576, 192, 0, stream>>>(qkv_w, qkv_b, bn_gamma, bn_beta, stats, w_eff, b_eff);
  wprep_k<<<784, 256, 0, stream>>>(dm_w, (__hip_bfloat16*)wTb2);
  pack_k<<<54, 256, 0, stream>>>(w_eff, pk_qkv, 192, 13824);
  pack_k<<<18, 256, 0, stream>>>(proj_w, pk_proj, 192, 4608);
  pack_k<<<72, 256, 0, stream>>>(c1_w, pk_c1, 192, 18432);
  pack_k<<<72, 256, 0, stream>>>(c2_w, pk_c2, 768, 18432);
  xT_k<<<dim3(BATCH * 49, 6), 256, 0, stream>>>(x, xT);

  mgemm_k<MG_QKV><<<dim3(49, 9), 256, 0, stream>>>(
      xT, pk_qkv, b_eff, vbuf, qkT, nullptr, 192);
  attn_mfma_k<<<NIMG * 49, 256, 0, stream>>>(qkT, wTb2, dm_b, rel_bias, attnL);
  softagg_k<<<NIMG * 49, 256, 0, stream>>>(attnL, vbuf, attnoT);
  mgemm_k<MG_PROJ><<<dim3(49, 3), 256, 0, stream>>>(
      attnoT, pk_proj, proj_b, x1, x1T, x, 192);
  mgemm_k<MG_GELU><<<dim3(49, 12), 256, 0, stream>>>(
      x1T, pk_c1, c1_b, nullptr, hT, nullptr, 192);
  mgemm_k<MG_C2><<<dim3(49, 3), 256, 0, stream>>>(
      hT, pk_c2, c2_b, out, nullptr, x1, 768);
}